// Round 4
// baseline (305.607 us; speedup 1.0000x reference)
//
#include <hip/hip_runtime.h>
#include <hip/hip_bf16.h>

#define NN 25000
#define NE 100000
#define NG 512
#define NPAD 25024
#define EB 1563        // edge blocks per branch (64 edges/block)
#define NB 391         // node blocks per branch (64 nodes/block)

typedef __attribute__((ext_vector_type(8))) short short8;
typedef __attribute__((ext_vector_type(4))) float f32x4;

__device__ __forceinline__ float bf2f(unsigned short u) {
    union { unsigned u; float f; } v; v.u = (unsigned)u << 16; return v.f;
}
__device__ __forceinline__ short f2bf(float f) {           // RTN-even
    union { float f; unsigned u; } v; v.f = f;
    return (short)((v.u + 0x7FFFu + ((v.u >> 16) & 1u)) >> 16);
}
__device__ __forceinline__ unsigned pk2(float lo, float hi) {
    return ((unsigned)(unsigned short)f2bf(hi) << 16) | (unsigned short)f2bf(lo);
}

// Wt layout per layer slot: 18 slices x [32 cols][32 k] bf16.
// slice s<16: w2[s*1024 + i*32 + o]; s==16: b2[i*32+o]; s==17: root[i*32+o].
struct PrepArgs {
    const float* w2[4]; const float* b2[4]; const float* root[4];
    const float* x0[2];
};
__global__ __launch_bounds__(256) void prep_kernel(PrepArgs pa,
        unsigned short* __restrict__ Wt, unsigned short* __restrict__ xb) {
    int idx = blockIdx.x * 256 + threadIdx.x;
    if (idx < 4 * 18 * 1024) {
        int L = idx / (18 * 1024);
        int r = idx % (18 * 1024);
        int s = r >> 10, o = (r >> 5) & 31, i = r & 31;
        float v;
        if (s < 16)      v = pa.w2[L][s * 1024 + i * 32 + o];
        else if (s == 16) v = pa.b2[L][i * 32 + o];
        else              v = pa.root[L][i * 32 + o];
        Wt[idx] = (unsigned short)f2bf(v);
        return;
    }
    int c = idx - 4 * 18 * 1024;
    if (c < 2 * NN * 32) {
        int br = c / (NN * 32);
        int r = c % (NN * 32);
        xb[(size_t)br * NPAD * 32 + r] = (unsigned short)f2bf(pa.x0[br][r]);
    }
}

// Per 16-edge tile (1 wave): h = relu(ea@w1+b1) [16x16];
// msg = [w2|b2]^T-slices (A) x Y (B), Y[k-slice s] = h[e,s] * x_bf16[src(e)]
// 17 slices x 2 row-tiles of mfma_f32_16x16x32_bf16; D cols = edges, rows = out.
// atomicAdd into agg[dst]. Both branches in one grid.
struct EdgeArgs {
    const float* ea[2]; const int* eidx[2];
    const float* w1[2]; const float* b1[2];
};
__global__ __launch_bounds__(256) void edge_kernel(EdgeArgs A, int L,
        const unsigned short* __restrict__ Wt,
        const unsigned short* __restrict__ xb,
        float* __restrict__ agg) {
    int br = blockIdx.x >= EB;
    int bb = blockIdx.x - br * EB;
    const float* ea   = A.ea[br];
    const int*   eidx = A.eidx[br];
    const float* w1   = A.w1[br];
    const float* b1   = A.b1[br];
    const unsigned short* W  = Wt + (size_t)(br * 2 + L) * 18 * 1024;
    const unsigned short* xc = xb + (size_t)br * NPAD * 32;
    float* ag = agg + (size_t)br * NPAD * 32;

    int tid = threadIdx.x;
    int wv = tid >> 6, lane = tid & 63;
    int lr = lane & 15, kg = lane >> 4;
    int e0 = (bb * 4 + wv) * 16;
    int e = e0 + lr;
    int ec = e < NE ? e : NE - 1;

    // gather x[src] fragment (16B bf16 -> fp32)
    int src = eidx[ec];
    short8 xs8 = *(const short8*)(xc + (size_t)src * 32 + kg * 8);
    float xf[8];
    #pragma unroll
    for (int j = 0; j < 8; ++j) xf[j] = bf2f((unsigned short)xs8[j]);

    // h[e][kg*4+r]
    float4 ea0 = *(const float4*)(ea + (size_t)ec * 8);
    float4 ea1 = *(const float4*)(ea + (size_t)ec * 8 + 4);
    float hreg[4];
    #pragma unroll
    for (int r = 0; r < 4; ++r) {
        int k = kg * 4 + r;
        float h = b1[k];
        h += ea0.x * w1[0 * 16 + k]; h += ea0.y * w1[1 * 16 + k];
        h += ea0.z * w1[2 * 16 + k]; h += ea0.w * w1[3 * 16 + k];
        h += ea1.x * w1[4 * 16 + k]; h += ea1.y * w1[5 * 16 + k];
        h += ea1.z * w1[6 * 16 + k]; h += ea1.w * w1[7 * 16 + k];
        hreg[r] = fmaxf(h, 0.f);
    }

    f32x4 acc0 = {0.f, 0.f, 0.f, 0.f}, acc1 = {0.f, 0.f, 0.f, 0.f};
    #pragma unroll
    for (int s = 0; s < 17; ++s) {
        float hs = (s < 16) ? __shfl(hreg[s & 3], lr + ((s >> 2) << 4), 64) : 1.0f;
        short8 y;
        #pragma unroll
        for (int j = 0; j < 8; ++j) y[j] = f2bf(hs * xf[j]);
        short8 a0 = *(const short8*)(W + (size_t)s * 1024 + lr * 32 + kg * 8);
        short8 a1 = *(const short8*)(W + (size_t)s * 1024 + (16 + lr) * 32 + kg * 8);
        acc0 = __builtin_amdgcn_mfma_f32_16x16x32_bf16(a0, y, acc0, 0, 0, 0);
        acc1 = __builtin_amdgcn_mfma_f32_16x16x32_bf16(a1, y, acc1, 0, 0, 0);
    }
    // D: col=lane&15 -> edge e; row=(lane>>4)*4+j -> out col kg*4+j (+16)
    if (e < NE) {
        int dst = eidx[NE + e];
        float* out = ag + (size_t)dst * 32;
        #pragma unroll
        for (int j = 0; j < 4; ++j) {
            atomicAdd(out + kg * 4 + j,      acc0[j]);
            atomicAdd(out + 16 + kg * 4 + j, acc1[j]);
        }
    }
}

// x' = relu(agg + x@root + bias); !LAST: write x in place (bf16) + zero agg;
// LAST: atomicMax into gbuf (global_max_pool). root MFMA: D cols = nodes.
struct CombArgs {
    const float* bias[2];
    const int* batch[2];
};
__global__ __launch_bounds__(256) void combine_kernel(CombArgs C, int L, int LAST,
        const unsigned short* __restrict__ Wt,
        unsigned short* __restrict__ xb,
        float* __restrict__ agg, float* __restrict__ gbuf) {
    int br = blockIdx.x >= NB;
    int bb = blockIdx.x - br * NB;
    const unsigned short* W = Wt + ((size_t)(br * 2 + L) * 18 + 17) * 1024;
    unsigned short* x = xb + (size_t)br * NPAD * 32;
    float* ag = agg + (size_t)br * NPAD * 32;
    const float* bias = C.bias[br];

    int tid = threadIdx.x;
    int wv = tid >> 6, lane = tid & 63;
    int lr = lane & 15, kg = lane >> 4;
    int n0 = (bb * 4 + wv) * 16;
    int n = n0 + lr;
    int nc = n < NN ? n : NN - 1;

    short8 xs = *(const short8*)(x + (size_t)nc * 32 + kg * 8);
    short8 a0 = *(const short8*)(W + lr * 32 + kg * 8);
    short8 a1 = *(const short8*)(W + (16 + lr) * 32 + kg * 8);
    f32x4 z = {0.f, 0.f, 0.f, 0.f};
    f32x4 d0 = __builtin_amdgcn_mfma_f32_16x16x32_bf16(a0, xs, z, 0, 0, 0);
    f32x4 d1 = __builtin_amdgcn_mfma_f32_16x16x32_bf16(a1, xs, z, 0, 0, 0);
    if (n >= NN) return;
    float4 g0 = *(const float4*)(ag + (size_t)n * 32 + kg * 4);
    float4 g1 = *(const float4*)(ag + (size_t)n * 32 + 16 + kg * 4);
    float v0[4], v1[4];
    v0[0] = fmaxf(d0[0] + g0.x + bias[kg * 4 + 0], 0.f);
    v0[1] = fmaxf(d0[1] + g0.y + bias[kg * 4 + 1], 0.f);
    v0[2] = fmaxf(d0[2] + g0.z + bias[kg * 4 + 2], 0.f);
    v0[3] = fmaxf(d0[3] + g0.w + bias[kg * 4 + 3], 0.f);
    v1[0] = fmaxf(d1[0] + g1.x + bias[16 + kg * 4 + 0], 0.f);
    v1[1] = fmaxf(d1[1] + g1.y + bias[16 + kg * 4 + 1], 0.f);
    v1[2] = fmaxf(d1[2] + g1.z + bias[16 + kg * 4 + 2], 0.f);
    v1[3] = fmaxf(d1[3] + g1.w + bias[16 + kg * 4 + 3], 0.f);
    if (!LAST) {
        unsigned* xw0 = (unsigned*)(x + (size_t)n * 32 + kg * 4);
        xw0[0] = pk2(v0[0], v0[1]); xw0[1] = pk2(v0[2], v0[3]);
        unsigned* xw1 = (unsigned*)(x + (size_t)n * 32 + 16 + kg * 4);
        xw1[0] = pk2(v1[0], v1[1]); xw1[1] = pk2(v1[2], v1[3]);
        float4 z4 = make_float4(0.f, 0.f, 0.f, 0.f);
        *(float4*)(ag + (size_t)n * 32 + kg * 4) = z4;
        *(float4*)(ag + (size_t)n * 32 + 16 + kg * 4) = z4;
    } else {
        int g = C.batch[br][n];
        float* gb = gbuf + (size_t)g * 64 + br * 32;
        #pragma unroll
        for (int j = 0; j < 4; ++j) {
            atomicMax((int*)(gb + kg * 4 + j),      __float_as_int(v0[j]));
            atomicMax((int*)(gb + 16 + kg * 4 + j), __float_as_int(v1[j]));
        }
    }
}

__global__ __launch_bounds__(64) void final_mlp_kernel(
        const float* __restrict__ gbuf,
        const float* __restrict__ w0, const float* __restrict__ b0,
        const float* __restrict__ w1v, const float* __restrict__ b1v,
        float* __restrict__ out) {
    int g = blockIdx.x;
    int j = threadIdx.x;
    const float* xr = gbuf + (size_t)g * 64;
    float y = b0[j];
    for (int i = 0; i < 64; ++i) y += xr[i] * w0[i * 64 + j];
    float t = y * w1v[j];
    #pragma unroll
    for (int off = 32; off > 0; off >>= 1) t += __shfl_down(t, off, 64);
    if (j == 0) out[g] = t + b1v[0];
}

extern "C" void kernel_launch(void* const* d_in, const int* in_sizes, int n_in,
                              void* d_out, int out_size, void* d_ws, size_t ws_size,
                              hipStream_t stream) {
    (void)in_sizes; (void)n_in; (void)out_size; (void)ws_size;
    char* w = (char*)d_ws;
    unsigned short* Wt  = (unsigned short*)w; w += (size_t)4 * 18 * 1024 * 2;   // 147 KB
    unsigned short* xb  = (unsigned short*)w; w += (size_t)2 * NPAD * 32 * 2;   // 3.2 MB
    float*          agg = (float*)w;          w += (size_t)2 * NPAD * 32 * 4;   // 6.4 MB
    float*          gbuf= (float*)w;          w += (size_t)NG * 64 * 4;         // 128 KB

    // agg and gbuf are adjacent: one memset zeroes both
    hipMemsetAsync(agg, 0, (size_t)2 * NPAD * 32 * 4 + (size_t)NG * 64 * 4, stream);

    PrepArgs pa;
    for (int L4 = 0; L4 < 4; ++L4) {
        int base = 8 + (L4 >> 1) * 12 + (L4 & 1) * 6;
        pa.w2[L4]   = (const float*)d_in[base + 2];
        pa.b2[L4]   = (const float*)d_in[base + 3];
        pa.root[L4] = (const float*)d_in[base + 4];
    }
    pa.x0[0] = (const float*)d_in[0];
    pa.x0[1] = (const float*)d_in[1];
    prep_kernel<<<(4 * 18 * 1024 + 2 * NN * 32) / 256, 256, 0, stream>>>(pa, Wt, xb);

    EdgeArgs ea; CombArgs ca;
    for (int br = 0; br < 2; ++br) {
        ea.ea[br]    = (const float*)d_in[2 + br];
        ea.eidx[br]  = (const int*)d_in[4 + br];
        ca.batch[br] = (const int*)d_in[6 + br];
    }
    for (int L = 0; L < 2; ++L) {
        for (int br = 0; br < 2; ++br) {
            int base = 8 + br * 12 + L * 6;
            ea.w1[br]   = (const float*)d_in[base + 0];
            ea.b1[br]   = (const float*)d_in[base + 1];
            ca.bias[br] = (const float*)d_in[base + 5];
        }
        edge_kernel<<<2 * EB, 256, 0, stream>>>(ea, L, Wt, xb, agg);
        combine_kernel<<<2 * NB, 256, 0, stream>>>(ca, L, (L == 1), Wt, xb, agg, gbuf);
    }

    final_mlp_kernel<<<NG, 64, 0, stream>>>(gbuf,
        (const float*)d_in[32], (const float*)d_in[33],
        (const float*)d_in[34], (const float*)d_in[35],
        (float*)d_out);
}

// Round 5
// 170.794 us; speedup vs baseline: 1.7893x; 1.7893x over previous
//
#include <hip/hip_runtime.h>

#define NN 25000
#define NE 100000
#define NG 512
#define NPAD 25024
#define NEP 100032          // padded msg rows (EB*64)
#define EB 1563             // edge blocks per branch (64 edges/block)
#define XL (2 * NPAD * 32)  // elements per x layer slot (both branches)

typedef __attribute__((ext_vector_type(8))) short short8;
typedef __attribute__((ext_vector_type(4))) float f32x4;

__device__ __forceinline__ float bf2f(unsigned short u) {
    union { unsigned u; float f; } v; v.u = (unsigned)u << 16; return v.f;
}
__device__ __forceinline__ unsigned short f2bf(float f) {   // RTN-even
    union { float f; unsigned u; } v; v.f = f;
    return (unsigned short)((v.u + 0x7FFFu + ((v.u >> 16) & 1u)) >> 16);
}
__device__ __forceinline__ unsigned pk2(float lo, float hi) {
    return ((unsigned)f2bf(hi) << 16) | f2bf(lo);
}

// ---------------- prep: Wt bf16 (17 slices: 16 w2 + b2), x0 cast, hist zero ----
struct PrepArgs {
    const float* w2[4]; const float* b2[4];
    const float* x0[2];
};
#define S1 (4 * 17 * 1024)
#define S2 (2 * NN * 32)
#define S3 (2 * NN)
__global__ __launch_bounds__(256) void prep_kernel(PrepArgs pa,
        unsigned short* __restrict__ Wt, unsigned short* __restrict__ xb,
        int* __restrict__ hist) {
    int idx = blockIdx.x * 256 + threadIdx.x;
    if (idx < S1) {
        int L = idx / (17 * 1024);
        int r = idx % (17 * 1024);
        int s = r >> 10, o = (r >> 5) & 31, i = r & 31;
        float v = (s < 16) ? pa.w2[L][s * 1024 + i * 32 + o] : pa.b2[L][i * 32 + o];
        Wt[idx] = f2bf(v);
        return;
    }
    idx -= S1;
    if (idx < S2) {
        int br = idx / (NN * 32);
        int r = idx % (NN * 32);
        xb[(size_t)br * NPAD * 32 + r] = f2bf(pa.x0[br][r]);
        return;
    }
    idx -= S2;
    if (idx < S3) hist[idx] = 0;
}

// ---------------- CSR build -------------------------------------------------
__global__ __launch_bounds__(256) void hist_kernel(const int* __restrict__ ep,
        const int* __restrict__ ed, int* __restrict__ hist) {
    int idx = blockIdx.x * 256 + threadIdx.x;
    if (idx >= 2 * NE) return;
    int br = idx >= NE, e = idx - br * NE;
    const int* ei = br ? ed : ep;
    atomicAdd(&hist[br * NN + ei[NE + e]], 1);
}

__global__ __launch_bounds__(1024) void scan_kernel(const int* __restrict__ hist,
        int* __restrict__ ptr, int* __restrict__ cursor) {
    int br = blockIdx.x, t = threadIdx.x;
    const int* h = hist + br * NN;
    int* p = ptr + br * (NN + 1);
    int* cur = cursor + br * NN;
    int base = t * 25;
    int loc[25]; int s = 0;
    if (base < NN) {
        #pragma unroll
        for (int j = 0; j < 25; ++j) { loc[j] = h[base + j]; s += loc[j]; }
    }
    __shared__ int ts[1024];
    ts[t] = s; __syncthreads();
    for (int d = 1; d < 1024; d <<= 1) {
        int v = (t >= d) ? ts[t - d] : 0;
        __syncthreads();
        ts[t] += v;
        __syncthreads();
    }
    int run = ts[t] - s;
    if (base < NN) {
        #pragma unroll
        for (int j = 0; j < 25; ++j) { p[base + j] = run; cur[base + j] = run; run += loc[j]; }
    }
    if (t == 1023) p[NN] = ts[1023];
}

__global__ __launch_bounds__(256) void scatter_kernel(const int* __restrict__ ep,
        const int* __restrict__ ed, int* __restrict__ cursor, int* __restrict__ eord) {
    int idx = blockIdx.x * 256 + threadIdx.x;
    if (idx >= 2 * NE) return;
    int br = idx >= NE, e = idx - br * NE;
    const int* ei = br ? ed : ep;
    int pos = atomicAdd(&cursor[br * NN + ei[NE + e]], 1);
    eord[br * NE + pos] = e;
}

// ---------------- edge: msg[e] = [w2|b2]^T (h(ea) (x) x[src]) ----------------
// 1 wave = 16 edges; MFMA D transposed through LDS -> lane-consecutive stores.
struct EdgeArgs {
    const float* ea[2]; const int* eidx[2];
    const float* w1[2]; const float* b1[2];
};
__global__ __launch_bounds__(256) void edge_kernel(EdgeArgs A, int L,
        const unsigned short* __restrict__ Wt,
        const unsigned short* __restrict__ xb,
        unsigned short* __restrict__ msg) {
    __shared__ unsigned tr[4][256];
    int br = blockIdx.x >= EB;
    int bb = blockIdx.x - br * EB;
    const float* ea   = A.ea[br];
    const int*   eidx = A.eidx[br];
    const float* w1   = A.w1[br];
    const float* b1   = A.b1[br];
    const unsigned short* W  = Wt + (size_t)(br * 2 + L) * 17 * 1024;
    const unsigned short* xc = xb + (size_t)L * XL + (size_t)br * NPAD * 32;

    int tid = threadIdx.x;
    int wv = tid >> 6, lane = tid & 63;
    int lr = lane & 15, kg = lane >> 4;
    int e0 = (bb * 4 + wv) * 16;
    int e = e0 + lr;
    int ec = e < NE ? e : NE - 1;

    int src = eidx[ec];
    short8 xs8 = *(const short8*)(xc + (size_t)src * 32 + kg * 8);
    float xf[8];
    #pragma unroll
    for (int j = 0; j < 8; ++j) xf[j] = bf2f((unsigned short)xs8[j]);

    float4 ea0 = *(const float4*)(ea + (size_t)ec * 8);
    float4 ea1 = *(const float4*)(ea + (size_t)ec * 8 + 4);
    float hreg[4];
    #pragma unroll
    for (int r = 0; r < 4; ++r) {
        int k = kg * 4 + r;
        float h = b1[k];
        h += ea0.x * w1[0 * 16 + k]; h += ea0.y * w1[1 * 16 + k];
        h += ea0.z * w1[2 * 16 + k]; h += ea0.w * w1[3 * 16 + k];
        h += ea1.x * w1[4 * 16 + k]; h += ea1.y * w1[5 * 16 + k];
        h += ea1.z * w1[6 * 16 + k]; h += ea1.w * w1[7 * 16 + k];
        hreg[r] = fmaxf(h, 0.f);
    }

    f32x4 acc0 = {0.f, 0.f, 0.f, 0.f}, acc1 = {0.f, 0.f, 0.f, 0.f};
    #pragma unroll
    for (int s = 0; s < 17; ++s) {
        short8 y;
        if (s < 16) {
            float hs = __shfl(hreg[s & 3], lr + ((s >> 2) << 4), 64);
            #pragma unroll
            for (int j = 0; j < 8; ++j) y[j] = f2bf(hs * xf[j]);
        } else {
            y = xs8;                       // b2 slice: h == 1
        }
        short8 a0 = *(const short8*)(W + (size_t)s * 1024 + lr * 32 + kg * 8);
        short8 a1 = *(const short8*)(W + (size_t)s * 1024 + (16 + lr) * 32 + kg * 8);
        acc0 = __builtin_amdgcn_mfma_f32_16x16x32_bf16(a0, y, acc0, 0, 0, 0);
        acc1 = __builtin_amdgcn_mfma_f32_16x16x32_bf16(a1, y, acc1, 0, 0, 0);
    }
    // D: col(lane&15)=edge lr, row=(kg*4+j)=out col. Pack to bf16 pairs, LDS transpose.
    tr[wv][lr * 16 + kg * 2    ] = pk2(acc0[0], acc0[1]);
    tr[wv][lr * 16 + kg * 2 + 1] = pk2(acc0[2], acc0[3]);
    tr[wv][lr * 16 + 8 + kg * 2    ] = pk2(acc1[0], acc1[1]);
    tr[wv][lr * 16 + 8 + kg * 2 + 1] = pk2(acc1[2], acc1[3]);
    // wave-internal LDS FIFO: reads below see the writes (no cross-wave traffic)
    unsigned* gm = (unsigned*)(msg + ((size_t)br * NEP + e0) * 32);
    gm[lane]       = tr[wv][lane];
    gm[lane + 64]  = tr[wv][lane + 64];
    gm[lane + 128] = tr[wv][lane + 128];
    gm[lane + 192] = tr[wv][lane + 192];
}

// ---------------- gather: x' = relu(sum msg[CSR] + x@root + bias) ------------
struct GatherArgs { const float* root[2]; const float* bias[2]; };
__global__ __launch_bounds__(256) void gather_kernel(GatherArgs G, int L,
        const int* __restrict__ ptr, const int* __restrict__ eord,
        const unsigned short* __restrict__ msg, unsigned short* __restrict__ xb) {
    int gw = (blockIdx.x * 256 + threadIdx.x) >> 5;   // node slot
    int o = threadIdx.x & 31;
    if (gw >= 2 * NN) return;
    int br = gw >= NN, n = gw - br * NN;
    const int* p = ptr + br * (NN + 1);
    int lo = p[n], hi = p[n + 1];
    const int* eo = eord + br * NE;
    const unsigned short* m = msg + (size_t)br * NEP * 32;
    float sum = 0.f;
    for (int j = lo; j < hi; ++j) {
        int e = eo[j];
        sum += bf2f(m[(size_t)e * 32 + o]);          // 32 lanes: one 64B row
    }
    const unsigned short* xin = xb + (size_t)L * XL + ((size_t)br * NPAD + n) * 32;
    float xv = bf2f(xin[o]);
    const float* R = G.root[br];
    float rsum = 0.f;
    #pragma unroll
    for (int i = 0; i < 32; ++i) {
        float xi = __shfl(xv, i, 32);
        rsum += xi * R[i * 32 + o];
    }
    float v = fmaxf(sum + rsum + G.bias[br][o], 0.f);
    unsigned short* xout = xb + (size_t)(L + 1) * XL + ((size_t)br * NPAD + n) * 32;
    xout[o] = f2bf(v);
}

// ---------------- segmax: block per graph, sorted batch -> binary search -----
struct SegArgs { const int* batch[2]; };
__global__ __launch_bounds__(256) void segmax_kernel(SegArgs S,
        const unsigned short* __restrict__ hf, float* __restrict__ gbuf) {
    int g = blockIdx.x;
    __shared__ float red[256];
    int o = threadIdx.x & 31, row = threadIdx.x >> 5;
    for (int br = 0; br < 2; ++br) {
        const int* b = S.batch[br];
        int lo = 0, hi = NN;
        while (lo < hi) { int mid = (lo + hi) >> 1; if (b[mid] < g) lo = mid + 1; else hi = mid; }
        int s0 = lo;
        hi = NN;
        while (lo < hi) { int mid = (lo + hi) >> 1; if (b[mid] < g + 1) lo = mid + 1; else hi = mid; }
        int s1 = lo;
        const unsigned short* h = hf + (size_t)br * NPAD * 32;
        float mv = 0.f;                                // relu'd values >= 0
        for (int n = s0 + row; n < s1; n += 8) mv = fmaxf(mv, bf2f(h[(size_t)n * 32 + o]));
        red[threadIdx.x] = mv; __syncthreads();
        if (row < 4) red[threadIdx.x] = fmaxf(red[threadIdx.x], red[threadIdx.x + 128]);
        __syncthreads();
        if (row < 2) red[threadIdx.x] = fmaxf(red[threadIdx.x], red[threadIdx.x + 64]);
        __syncthreads();
        if (row == 0)
            gbuf[(size_t)g * 64 + br * 32 + o] = fmaxf(red[threadIdx.x], red[threadIdx.x + 32]);
        __syncthreads();
    }
}

// ---------------- final MLP --------------------------------------------------
__global__ __launch_bounds__(64) void final_mlp_kernel(
        const float* __restrict__ gbuf,
        const float* __restrict__ w0, const float* __restrict__ b0,
        const float* __restrict__ w1v, const float* __restrict__ b1v,
        float* __restrict__ out) {
    int g = blockIdx.x;
    int j = threadIdx.x;
    const float* xr = gbuf + (size_t)g * 64;
    float y = b0[j];
    for (int i = 0; i < 64; ++i) y += xr[i] * w0[i * 64 + j];
    float t = y * w1v[j];
    #pragma unroll
    for (int off = 32; off > 0; off >>= 1) t += __shfl_down(t, off, 64);
    if (j == 0) out[g] = t + b1v[0];
}

extern "C" void kernel_launch(void* const* d_in, const int* in_sizes, int n_in,
                              void* d_out, int out_size, void* d_ws, size_t ws_size,
                              hipStream_t stream) {
    (void)in_sizes; (void)n_in; (void)out_size; (void)ws_size;
    char* w = (char*)d_ws;
    unsigned short* Wt  = (unsigned short*)w; w += (size_t)S1 * 2;               // 136 KB
    unsigned short* xb  = (unsigned short*)w; w += (size_t)3 * XL * 2;           // 9.6 MB
    unsigned short* msg = (unsigned short*)w; w += (size_t)2 * NEP * 32 * 2;     // 12.8 MB
    int* hist   = (int*)w; w += (size_t)2 * NN * 4;
    int* ptr    = (int*)w; w += (size_t)2 * (NN + 1) * 4;
    int* cursor = (int*)w; w += (size_t)2 * NN * 4;
    int* eord   = (int*)w; w += (size_t)2 * NE * 4;
    float* gbuf = (float*)w; w += (size_t)NG * 64 * 4;

    const int* ep = (const int*)d_in[4];
    const int* ed = (const int*)d_in[5];

    PrepArgs pa;
    for (int L4 = 0; L4 < 4; ++L4) {
        int base = 8 + (L4 >> 1) * 12 + (L4 & 1) * 6;
        pa.w2[L4] = (const float*)d_in[base + 2];
        pa.b2[L4] = (const float*)d_in[base + 3];
    }
    pa.x0[0] = (const float*)d_in[0];
    pa.x0[1] = (const float*)d_in[1];
    prep_kernel<<<(S1 + S2 + S3 + 255) / 256, 256, 0, stream>>>(pa, Wt, xb, hist);

    hist_kernel<<<(2 * NE + 255) / 256, 256, 0, stream>>>(ep, ed, hist);
    scan_kernel<<<2, 1024, 0, stream>>>(hist, ptr, cursor);
    scatter_kernel<<<(2 * NE + 255) / 256, 256, 0, stream>>>(ep, ed, cursor, eord);

    EdgeArgs ea; GatherArgs ga;
    for (int br = 0; br < 2; ++br) {
        ea.ea[br]   = (const float*)d_in[2 + br];
        ea.eidx[br] = (const int*)d_in[4 + br];
    }
    for (int L = 0; L < 2; ++L) {
        for (int br = 0; br < 2; ++br) {
            int base = 8 + br * 12 + L * 6;
            ea.w1[br]   = (const float*)d_in[base + 0];
            ea.b1[br]   = (const float*)d_in[base + 1];
            ga.root[br] = (const float*)d_in[base + 4];
            ga.bias[br] = (const float*)d_in[base + 5];
        }
        edge_kernel<<<2 * EB, 256, 0, stream>>>(ea, L, Wt, xb, msg);
        gather_kernel<<<(2 * NN * 32 + 255) / 256, 256, 0, stream>>>(ga, L, ptr, eord, msg, xb);
    }

    SegArgs sa;
    sa.batch[0] = (const int*)d_in[6];
    sa.batch[1] = (const int*)d_in[7];
    segmax_kernel<<<NG, 256, 0, stream>>>(sa, xb + (size_t)2 * XL, gbuf);

    final_mlp_kernel<<<NG, 64, 0, stream>>>(gbuf,
        (const float*)d_in[32], (const float*)d_in[33],
        (const float*)d_in[34], (const float*)d_in[35],
        (float*)d_out);
}

// Round 6
// 118.107 us; speedup vs baseline: 2.5875x; 1.4461x over previous
//
#include <hip/hip_runtime.h>
#include <hip/hip_bf16.h>

#define NN 25000
#define NE 100000
#define NG 512
#define NPAD 25024
#define NEP 100032          // padded msg rows
#define NT 6250             // edge tiles per branch (NE/16, exact)
#define XL (2 * NPAD * 32)  // elements per x layer slot (both branches)

typedef __attribute__((ext_vector_type(8))) short short8;
typedef __attribute__((ext_vector_type(4))) float f32x4;

__device__ __forceinline__ float bf2f(unsigned short u) {
    union { unsigned u; float f; } v; v.u = (unsigned)u << 16; return v.f;
}
__device__ __forceinline__ unsigned short f2bf(float f) {       // native RNE cast
    union { __hip_bfloat16 b; unsigned short u; } c;
    c.b = __float2bfloat16(f);
    return c.u;
}
__device__ __forceinline__ unsigned pk2(float lo, float hi) {   // packed bf16 pair
    __hip_bfloat162 h2;
    h2.x = __float2bfloat16(lo);
    h2.y = __float2bfloat16(hi);
    union { __hip_bfloat162 h; unsigned u; } c; c.h = h2; return c.u;
}

// ---------------- prep: Wt bf16 (17 slices: 16 w2 + b2), x0 cast, hist zero ---
struct PrepArgs {
    const float* w2[4]; const float* b2[4];
    const float* x0[2];
};
#define S1 (4 * 17 * 1024)
#define S2 (2 * NN * 32)
#define S3 (2 * NN)
__global__ __launch_bounds__(256) void prep_kernel(PrepArgs pa,
        unsigned short* __restrict__ Wt, unsigned short* __restrict__ xb,
        int* __restrict__ hist) {
    int idx = blockIdx.x * 256 + threadIdx.x;
    if (idx < S1) {
        int L = idx / (17 * 1024);
        int r = idx % (17 * 1024);
        int s = r >> 10, o = (r >> 5) & 31, i = r & 31;
        float v = (s < 16) ? pa.w2[L][s * 1024 + i * 32 + o] : pa.b2[L][i * 32 + o];
        Wt[idx] = f2bf(v);
        return;
    }
    idx -= S1;
    if (idx < S2) {
        int br = idx / (NN * 32);
        int r = idx % (NN * 32);
        xb[(size_t)br * NPAD * 32 + r] = f2bf(pa.x0[br][r]);
        return;
    }
    idx -= S2;
    if (idx < S3) hist[idx] = 0;
}

// ---------------- CSR: hist + within-dst slot ---------------------------------
__global__ __launch_bounds__(256) void hist_kernel(const int* __restrict__ ep,
        const int* __restrict__ ed, int* __restrict__ hist, int* __restrict__ slot) {
    int idx = blockIdx.x * 256 + threadIdx.x;
    if (idx >= 2 * NE) return;
    int br = idx >= NE, e = idx - br * NE;
    const int* ei = br ? ed : ep;
    slot[idx] = atomicAdd(&hist[br * NN + ei[NE + e]], 1);
}

// shfl-based scan: 1024 threads x 25 elems, 2 blocks (one per branch)
__global__ __launch_bounds__(1024) void scan_kernel(const int* __restrict__ hist,
        int* __restrict__ ptr) {
    int br = blockIdx.x, t = threadIdx.x;
    const int* h = hist + br * NN;
    int* p = ptr + br * (NN + 1);
    int base = t * 25;
    int loc[25]; int s = 0;
    if (base < NN) {
        #pragma unroll
        for (int j = 0; j < 25; ++j) { loc[j] = h[base + j]; s += loc[j]; }
    }
    int w = t >> 6, ln = t & 63;
    int v = s;
    #pragma unroll
    for (int d = 1; d < 64; d <<= 1) {
        int u = __shfl_up(v, d, 64);
        if (ln >= d) v += u;
    }
    __shared__ int wsum[16];
    if (ln == 63) wsum[w] = v;
    __syncthreads();
    if (t < 16) {
        int x = wsum[t];
        #pragma unroll
        for (int d = 1; d < 16; d <<= 1) {
            int u = __shfl_up(x, d, 16);
            if ((t & 15) >= d) x += u;
        }
        wsum[t] = x;
    }
    __syncthreads();
    int run = (w ? wsum[w - 1] : 0) + (v - s);
    if (base < NN) {
        #pragma unroll
        for (int j = 0; j < 25; ++j) { p[base + j] = run; run += loc[j]; }
    }
    if (t == 0) p[NN] = wsum[15];
}

// ---------------- edge: msg[rank(e)] = [w2|b2]^T (h(ea) (x) x[src]) -----------
// W resident in VGPRs (34 x short8); grid-stride over 16-edge tiles.
// Output rows written at CSR rank -> gather streams sequentially.
struct EdgeArgs {
    const float* ea[2]; const int* eidx[2];
    const float* w1[2]; const float* b1[2];
};
__global__ __launch_bounds__(256, 2) void edge_kernel(EdgeArgs A, int L,
        const unsigned short* __restrict__ Wt,
        const unsigned short* __restrict__ xb,
        const int* __restrict__ ptr, const int* __restrict__ slot,
        unsigned short* __restrict__ msg) {
    __shared__ unsigned tr[4][256];
    int br = blockIdx.x >> 8;          // 512 blocks: low 256 = branch 0
    int bb = blockIdx.x & 255;
    const float* ea   = A.ea[br];
    const int*   eidx = A.eidx[br];
    const float* w1   = A.w1[br];
    const float* b1   = A.b1[br];
    const unsigned short* W  = Wt + (size_t)(br * 2 + L) * 17 * 1024;
    const unsigned short* xc = xb + (size_t)L * XL + (size_t)br * NPAD * 32;
    const int* pt = ptr + br * (NN + 1);
    const int* sl = slot + br * NE;
    unsigned short* mg = msg + (size_t)br * NEP * 32;

    int tid = threadIdx.x;
    int wv = tid >> 6, lane = tid & 63;
    int lr = lane & 15, kg = lane >> 4;

    // W tiles resident in registers for the whole kernel
    short8 WA[17], WB[17];
    #pragma unroll
    for (int s = 0; s < 17; ++s) {
        WA[s] = *(const short8*)(W + (size_t)s * 1024 + lr * 32 + kg * 8);
        WB[s] = *(const short8*)(W + (size_t)s * 1024 + (16 + lr) * 32 + kg * 8);
    }
    // w1 columns for this lane's 4 k-values
    float w1r[32], b1r[4];
    #pragma unroll
    for (int r = 0; r < 4; ++r) {
        b1r[r] = b1[kg * 4 + r];
        #pragma unroll
        for (int i = 0; i < 8; ++i) w1r[r * 8 + i] = w1[i * 16 + kg * 4 + r];
    }

    for (int t = bb * 4 + wv; t < NT; t += 1024) {
        int e = t * 16 + lr;
        int src = eidx[e];
        int rk = 0;
        if (kg == 0) rk = pt[eidx[NE + e]] + sl[e];

        short8 xs8 = *(const short8*)(xc + (size_t)src * 32 + kg * 8);
        float xf[8];
        #pragma unroll
        for (int j = 0; j < 8; ++j) xf[j] = bf2f((unsigned short)xs8[j]);

        float4 ea0 = *(const float4*)(ea + (size_t)e * 8);
        float4 ea1 = *(const float4*)(ea + (size_t)e * 8 + 4);
        float hreg[4];
        #pragma unroll
        for (int r = 0; r < 4; ++r) {
            float h = b1r[r];
            h += ea0.x * w1r[r * 8 + 0]; h += ea0.y * w1r[r * 8 + 1];
            h += ea0.z * w1r[r * 8 + 2]; h += ea0.w * w1r[r * 8 + 3];
            h += ea1.x * w1r[r * 8 + 4]; h += ea1.y * w1r[r * 8 + 5];
            h += ea1.z * w1r[r * 8 + 6]; h += ea1.w * w1r[r * 8 + 7];
            hreg[r] = fmaxf(h, 0.f);
        }

        f32x4 acc0 = {0.f, 0.f, 0.f, 0.f}, acc1 = {0.f, 0.f, 0.f, 0.f};
        #pragma unroll
        for (int s = 0; s < 17; ++s) {
            short8 y;
            if (s < 16) {
                float hs = __shfl(hreg[s & 3], lr + ((s >> 2) << 4), 64);
                union { unsigned u[4]; short8 v; } yy;
                yy.u[0] = pk2(hs * xf[0], hs * xf[1]);
                yy.u[1] = pk2(hs * xf[2], hs * xf[3]);
                yy.u[2] = pk2(hs * xf[4], hs * xf[5]);
                yy.u[3] = pk2(hs * xf[6], hs * xf[7]);
                y = yy.v;
            } else {
                y = xs8;                    // b2 slice: h == 1
            }
            acc0 = __builtin_amdgcn_mfma_f32_16x16x32_bf16(WA[s], y, acc0, 0, 0, 0);
            acc1 = __builtin_amdgcn_mfma_f32_16x16x32_bf16(WB[s], y, acc1, 0, 0, 0);
        }
        // transpose through wave-private LDS, then one dwordx4 store per lane
        tr[wv][lr * 16 + kg * 2    ] = pk2(acc0[0], acc0[1]);
        tr[wv][lr * 16 + kg * 2 + 1] = pk2(acc0[2], acc0[3]);
        tr[wv][lr * 16 + 8 + kg * 2    ] = pk2(acc1[0], acc1[1]);
        tr[wv][lr * 16 + 8 + kg * 2 + 1] = pk2(acc1[2], acc1[3]);
        int rkb = __shfl(rk, lane >> 2, 64);
        uint4 val = *(uint4*)&tr[wv][(lane >> 2) * 16 + (lane & 3) * 4];
        *(uint4*)(mg + (size_t)rkb * 32 + (lane & 3) * 8) = val;
    }
}

// ---------------- gather: x' = relu(sum msg[lo..hi) + x@root + bias) ----------
// msg rows contiguous per node (CSR order) -> streaming reads.
struct GatherArgs { const float* root[2]; const float* bias[2]; const int* batch[2]; };
template<int LAST>
__global__ __launch_bounds__(256) void gather_kernel(GatherArgs G,
        const int* __restrict__ ptr, const unsigned short* __restrict__ msg,
        const unsigned short* __restrict__ xin_, unsigned short* __restrict__ xout_,
        float* __restrict__ gbuf) {
    int gw = (blockIdx.x * 256 + threadIdx.x) >> 5;   // node slot (exact grid)
    int o = threadIdx.x & 31;
    int br = gw >= NN, n = gw - br * NN;
    const int* p = ptr + br * (NN + 1);
    int lo = p[n], hi = p[n + 1];
    const unsigned short* m = msg + (size_t)br * NEP * 32;
    float sum = 0.f;
    for (int j = lo; j < hi; ++j) sum += bf2f(m[(size_t)j * 32 + o]);
    float xv = bf2f(xin_[(size_t)br * NPAD * 32 + (size_t)n * 32 + o]);
    const float* R = G.root[br];
    float rsum = 0.f;
    #pragma unroll
    for (int i = 0; i < 32; ++i) rsum += __shfl(xv, i, 32) * R[i * 32 + o];
    float v = fmaxf(sum + rsum + G.bias[br][o], 0.f);
    if (!LAST) {
        xout_[(size_t)br * NPAD * 32 + (size_t)n * 32 + o] = f2bf(v);
    } else {
        int g = G.batch[br][n];
        atomicMax((int*)&gbuf[(size_t)g * 64 + br * 32 + o], __float_as_int(v));
    }
}

// ---------------- final MLP ---------------------------------------------------
__global__ __launch_bounds__(64) void final_mlp_kernel(
        const float* __restrict__ gbuf,
        const float* __restrict__ w0, const float* __restrict__ b0,
        const float* __restrict__ w1v, const float* __restrict__ b1v,
        float* __restrict__ out) {
    int g = blockIdx.x;
    int j = threadIdx.x;
    const float* xr = gbuf + (size_t)g * 64;
    float y = b0[j];
    for (int i = 0; i < 64; ++i) y += xr[i] * w0[i * 64 + j];
    float t = y * w1v[j];
    #pragma unroll
    for (int off = 32; off > 0; off >>= 1) t += __shfl_down(t, off, 64);
    if (j == 0) out[g] = t + b1v[0];
}

static size_t aln(size_t v) { return (v + 255) & ~(size_t)255; }

extern "C" void kernel_launch(void* const* d_in, const int* in_sizes, int n_in,
                              void* d_out, int out_size, void* d_ws, size_t ws_size,
                              hipStream_t stream) {
    (void)in_sizes; (void)n_in; (void)out_size; (void)ws_size;
    char* w = (char*)d_ws;
    unsigned short* Wt  = (unsigned short*)w; w += aln((size_t)S1 * 2);
    unsigned short* xb  = (unsigned short*)w; w += aln((size_t)2 * XL * 2);          // 2 layer slots
    unsigned short* msg = (unsigned short*)w; w += aln((size_t)2 * NEP * 32 * 2);    // 12.8 MB
    int* hist = (int*)w; w += aln((size_t)2 * NN * 4);
    int* ptr  = (int*)w; w += aln((size_t)2 * (NN + 1) * 4);
    int* slot = (int*)w; w += aln((size_t)2 * NE * 4);
    float* gbuf = (float*)w; w += aln((size_t)NG * 64 * 4);

    const int* ep = (const int*)d_in[4];
    const int* ed = (const int*)d_in[5];

    hipMemsetAsync(gbuf, 0, (size_t)NG * 64 * sizeof(float), stream);

    PrepArgs pa;
    for (int L4 = 0; L4 < 4; ++L4) {
        int base = 8 + (L4 >> 1) * 12 + (L4 & 1) * 6;
        pa.w2[L4] = (const float*)d_in[base + 2];
        pa.b2[L4] = (const float*)d_in[base + 3];
    }
    pa.x0[0] = (const float*)d_in[0];
    pa.x0[1] = (const float*)d_in[1];
    prep_kernel<<<(S1 + S2 + S3 + 255) / 256, 256, 0, stream>>>(pa, Wt, xb, hist);

    hist_kernel<<<(2 * NE + 255) / 256, 256, 0, stream>>>(ep, ed, hist, slot);
    scan_kernel<<<2, 1024, 0, stream>>>(hist, ptr);

    EdgeArgs ea; GatherArgs ga;
    for (int br = 0; br < 2; ++br) {
        ea.ea[br]    = (const float*)d_in[2 + br];
        ea.eidx[br]  = (const int*)d_in[4 + br];
        ga.batch[br] = (const int*)d_in[6 + br];
    }
    for (int L = 0; L < 2; ++L) {
        for (int br = 0; br < 2; ++br) {
            int base = 8 + br * 12 + L * 6;
            ea.w1[br]   = (const float*)d_in[base + 0];
            ea.b1[br]   = (const float*)d_in[base + 1];
            ga.root[br] = (const float*)d_in[base + 4];
            ga.bias[br] = (const float*)d_in[base + 5];
        }
        edge_kernel<<<512, 256, 0, stream>>>(ea, L, Wt, xb, ptr, slot, msg);
        if (L == 0)
            gather_kernel<0><<<6250, 256, 0, stream>>>(ga, ptr, msg,
                xb, xb + (size_t)XL, gbuf);
        else
            gather_kernel<1><<<6250, 256, 0, stream>>>(ga, ptr, msg,
                xb + (size_t)XL, nullptr, gbuf);
    }

    final_mlp_kernel<<<NG, 64, 0, stream>>>(gbuf,
        (const float*)d_in[32], (const float*)d_in[33],
        (const float*)d_in[34], (const float*)d_in[35],
        (float*)d_out);
}

// Round 7
// 113.019 us; speedup vs baseline: 2.7040x; 1.0450x over previous
//
#include <hip/hip_runtime.h>
#include <hip/hip_bf16.h>

#define NN 25000
#define NE 100000
#define NG 512
#define NPAD 25024
#define NEP 100032          // padded msg rows
#define NT 6250             // edge tiles per branch (NE/16, exact)
#define XL (2 * NPAD * 32)  // elements per x layer slot (both branches)

typedef __attribute__((ext_vector_type(8))) short short8;
typedef __attribute__((ext_vector_type(4))) float f32x4;

__device__ __forceinline__ float bf2f(unsigned short u) {
    union { unsigned u; float f; } v; v.u = (unsigned)u << 16; return v.f;
}
__device__ __forceinline__ unsigned short f2bf(float f) {       // native RNE cast
    union { __hip_bfloat16 b; unsigned short u; } c;
    c.b = __float2bfloat16(f);
    return c.u;
}
__device__ __forceinline__ unsigned pk2(float lo, float hi) {   // packed bf16 pair
    __hip_bfloat162 h2;
    h2.x = __float2bfloat16(lo);
    h2.y = __float2bfloat16(hi);
    union { __hip_bfloat162 h; unsigned u; } c; c.h = h2; return c.u;
}

// ---- prep: Wt bf16 (17 slices: 16 w2 + b2), x0 cast (x4 vec), hist+gbuf zero --
struct PrepArgs {
    const float* w2[4]; const float* b2[4];
    const float* x0[2];
};
#define S1 (4 * 17 * 1024)
#define S2V (2 * NN * 8)        // float4-vectorized x cast items
#define S3 (2 * NN)
#define S4 (NG * 64 / 4)        // gbuf zero, float4 items
__global__ __launch_bounds__(256) void prep_kernel(PrepArgs pa,
        unsigned short* __restrict__ Wt, unsigned short* __restrict__ xb,
        int* __restrict__ hist, float* __restrict__ gbuf) {
    int idx = blockIdx.x * 256 + threadIdx.x;
    if (idx < S1) {
        int L = idx / (17 * 1024);
        int r = idx % (17 * 1024);
        int s = r >> 10, o = (r >> 5) & 31, i = r & 31;
        float v = (s < 16) ? pa.w2[L][s * 1024 + i * 32 + o] : pa.b2[L][i * 32 + o];
        Wt[idx] = f2bf(v);
        return;
    }
    idx -= S1;
    if (idx < S2V) {
        int br = idx / (NN * 8);
        int q = idx % (NN * 8);
        float4 v = *(const float4*)(pa.x0[br] + (size_t)q * 4);
        unsigned* dst = (unsigned*)(xb + (size_t)br * NPAD * 32 + (size_t)q * 4);
        dst[0] = pk2(v.x, v.y);
        dst[1] = pk2(v.z, v.w);
        return;
    }
    idx -= S2V;
    if (idx < S3) { hist[idx] = 0; return; }
    idx -= S3;
    if (idx < S4) {
        float4 z = make_float4(0.f, 0.f, 0.f, 0.f);
        *(float4*)(gbuf + (size_t)idx * 4) = z;
    }
}

// ---------------- CSR: hist + within-dst slot ---------------------------------
__global__ __launch_bounds__(256) void hist_kernel(const int* __restrict__ ep,
        const int* __restrict__ ed, int* __restrict__ hist, int* __restrict__ slot) {
    int idx = blockIdx.x * 256 + threadIdx.x;
    if (idx >= 2 * NE) return;
    int br = idx >= NE, e = idx - br * NE;
    const int* ei = br ? ed : ep;
    slot[idx] = atomicAdd(&hist[br * NN + ei[NE + e]], 1);
}

// shfl-based scan: 1024 threads x 25 elems, 2 blocks (one per branch)
__global__ __launch_bounds__(1024) void scan_kernel(const int* __restrict__ hist,
        int* __restrict__ ptr) {
    int br = blockIdx.x, t = threadIdx.x;
    const int* h = hist + br * NN;
    int* p = ptr + br * (NN + 1);
    int base = t * 25;
    int loc[25]; int s = 0;
    if (base < NN) {
        #pragma unroll
        for (int j = 0; j < 25; ++j) { loc[j] = h[base + j]; s += loc[j]; }
    }
    int w = t >> 6, ln = t & 63;
    int v = s;
    #pragma unroll
    for (int d = 1; d < 64; d <<= 1) {
        int u = __shfl_up(v, d, 64);
        if (ln >= d) v += u;
    }
    __shared__ int wsum[16];
    if (ln == 63) wsum[w] = v;
    __syncthreads();
    if (t < 16) {
        int x = wsum[t];
        #pragma unroll
        for (int d = 1; d < 16; d <<= 1) {
            int u = __shfl_up(x, d, 16);
            if ((t & 15) >= d) x += u;
        }
        wsum[t] = x;
    }
    __syncthreads();
    int run = (w ? wsum[w - 1] : 0) + (v - s);
    if (base < NN) {
        #pragma unroll
        for (int j = 0; j < 25; ++j) { p[base + j] = run; run += loc[j]; }
    }
    if (t == 0) p[NN] = wsum[15];
}

// ---------------- edge: msg[rank(e)] = [w2|b2]^T (h(ea) (x) x[src]) -----------
// W resident in VGPRs (34 x short8); grid-stride over 16-edge tiles.
// Output rows written at CSR rank -> gather streams sequentially.
struct EdgeArgs {
    const float* ea[2]; const int* eidx[2];
    const float* w1[2]; const float* b1[2];
};
__global__ __launch_bounds__(256, 2) void edge_kernel(EdgeArgs A, int L,
        const unsigned short* __restrict__ Wt,
        const unsigned short* __restrict__ xb,
        const int* __restrict__ ptr, const int* __restrict__ slot,
        unsigned short* __restrict__ msg) {
    __shared__ unsigned tr[4][256];
    int br = blockIdx.x >> 8;          // 512 blocks: low 256 = branch 0
    int bb = blockIdx.x & 255;
    const float* ea   = A.ea[br];
    const int*   eidx = A.eidx[br];
    const float* w1   = A.w1[br];
    const float* b1   = A.b1[br];
    const unsigned short* W  = Wt + (size_t)(br * 2 + L) * 17 * 1024;
    const unsigned short* xc = xb + (size_t)L * XL + (size_t)br * NPAD * 32;
    const int* pt = ptr + br * (NN + 1);
    const int* sl = slot + br * NE;
    unsigned short* mg = msg + (size_t)br * NEP * 32;

    int tid = threadIdx.x;
    int wv = tid >> 6, lane = tid & 63;
    int lr = lane & 15, kg = lane >> 4;

    // W tiles resident in registers for the whole kernel
    short8 WA[17], WB[17];
    #pragma unroll
    for (int s = 0; s < 17; ++s) {
        WA[s] = *(const short8*)(W + (size_t)s * 1024 + lr * 32 + kg * 8);
        WB[s] = *(const short8*)(W + (size_t)s * 1024 + (16 + lr) * 32 + kg * 8);
    }
    // w1 columns for this lane's 4 k-values
    float w1r[32], b1r[4];
    #pragma unroll
    for (int r = 0; r < 4; ++r) {
        b1r[r] = b1[kg * 4 + r];
        #pragma unroll
        for (int i = 0; i < 8; ++i) w1r[r * 8 + i] = w1[i * 16 + kg * 4 + r];
    }

    for (int t = bb * 4 + wv; t < NT; t += 1024) {
        int e = t * 16 + lr;
        int src = eidx[e];
        int rk = 0;
        if (kg == 0) rk = pt[eidx[NE + e]] + sl[e];

        short8 xs8 = *(const short8*)(xc + (size_t)src * 32 + kg * 8);
        float xf[8];
        #pragma unroll
        for (int j = 0; j < 8; ++j) xf[j] = bf2f((unsigned short)xs8[j]);

        float4 ea0 = *(const float4*)(ea + (size_t)e * 8);
        float4 ea1 = *(const float4*)(ea + (size_t)e * 8 + 4);
        float hreg[4];
        #pragma unroll
        for (int r = 0; r < 4; ++r) {
            float h = b1r[r];
            h += ea0.x * w1r[r * 8 + 0]; h += ea0.y * w1r[r * 8 + 1];
            h += ea0.z * w1r[r * 8 + 2]; h += ea0.w * w1r[r * 8 + 3];
            h += ea1.x * w1r[r * 8 + 4]; h += ea1.y * w1r[r * 8 + 5];
            h += ea1.z * w1r[r * 8 + 6]; h += ea1.w * w1r[r * 8 + 7];
            hreg[r] = fmaxf(h, 0.f);
        }

        f32x4 acc0 = {0.f, 0.f, 0.f, 0.f}, acc1 = {0.f, 0.f, 0.f, 0.f};
        #pragma unroll
        for (int s = 0; s < 17; ++s) {
            short8 y;
            if (s < 16) {
                float hs = __shfl(hreg[s & 3], lr + ((s >> 2) << 4), 64);
                union { unsigned u[4]; short8 v; } yy;
                yy.u[0] = pk2(hs * xf[0], hs * xf[1]);
                yy.u[1] = pk2(hs * xf[2], hs * xf[3]);
                yy.u[2] = pk2(hs * xf[4], hs * xf[5]);
                yy.u[3] = pk2(hs * xf[6], hs * xf[7]);
                y = yy.v;
            } else {
                y = xs8;                    // b2 slice: h == 1
            }
            acc0 = __builtin_amdgcn_mfma_f32_16x16x32_bf16(WA[s], y, acc0, 0, 0, 0);
            acc1 = __builtin_amdgcn_mfma_f32_16x16x32_bf16(WB[s], y, acc1, 0, 0, 0);
        }
        // transpose through wave-private LDS, then one dwordx4 store per lane
        tr[wv][lr * 16 + kg * 2    ] = pk2(acc0[0], acc0[1]);
        tr[wv][lr * 16 + kg * 2 + 1] = pk2(acc0[2], acc0[3]);
        tr[wv][lr * 16 + 8 + kg * 2    ] = pk2(acc1[0], acc1[1]);
        tr[wv][lr * 16 + 8 + kg * 2 + 1] = pk2(acc1[2], acc1[3]);
        int rkb = __shfl(rk, lane >> 2, 64);
        uint4 val = *(uint4*)&tr[wv][(lane >> 2) * 16 + (lane & 3) * 4];
        *(uint4*)(mg + (size_t)rkb * 32 + (lane & 3) * 8) = val;
    }
}

// ---------------- gather: x' = relu(sum msg[lo..hi) + x@root + bias) ----------
// msg rows contiguous per node (CSR order) -> streaming reads.
struct GatherArgs { const float* root[2]; const float* bias[2]; const int* batch[2]; };
template<int LAST>
__global__ __launch_bounds__(256) void gather_kernel(GatherArgs G,
        const int* __restrict__ ptr, const unsigned short* __restrict__ msg,
        const unsigned short* __restrict__ xin_, unsigned short* __restrict__ xout_,
        float* __restrict__ gbuf) {
    int gw = (blockIdx.x * 256 + threadIdx.x) >> 5;   // node slot (exact grid)
    int o = threadIdx.x & 31;
    int br = gw >= NN, n = gw - br * NN;
    const int* p = ptr + br * (NN + 1);
    int lo = p[n], hi = p[n + 1];
    const unsigned short* m = msg + (size_t)br * NEP * 32;
    float sum = 0.f;
    for (int j = lo; j < hi; ++j) sum += bf2f(m[(size_t)j * 32 + o]);
    float xv = bf2f(xin_[(size_t)br * NPAD * 32 + (size_t)n * 32 + o]);
    const float* R = G.root[br];
    float rsum = 0.f;
    #pragma unroll
    for (int i = 0; i < 32; ++i) rsum += __shfl(xv, i, 32) * R[i * 32 + o];
    float v = fmaxf(sum + rsum + G.bias[br][o], 0.f);
    if (!LAST) {
        xout_[(size_t)br * NPAD * 32 + (size_t)n * 32 + o] = f2bf(v);
    } else {
        int g = G.batch[br][n];
        atomicMax((int*)&gbuf[(size_t)g * 64 + br * 32 + o], __float_as_int(v));
    }
}

// ---------------- final MLP ---------------------------------------------------
__global__ __launch_bounds__(64) void final_mlp_kernel(
        const float* __restrict__ gbuf,
        const float* __restrict__ w0, const float* __restrict__ b0,
        const float* __restrict__ w1v, const float* __restrict__ b1v,
        float* __restrict__ out) {
    int g = blockIdx.x;
    int j = threadIdx.x;
    const float* xr = gbuf + (size_t)g * 64;
    float y = b0[j];
    for (int i = 0; i < 64; ++i) y += xr[i] * w0[i * 64 + j];
    float t = y * w1v[j];
    #pragma unroll
    for (int off = 32; off > 0; off >>= 1) t += __shfl_down(t, off, 64);
    if (j == 0) out[g] = t + b1v[0];
}

static size_t aln(size_t v) { return (v + 255) & ~(size_t)255; }

extern "C" void kernel_launch(void* const* d_in, const int* in_sizes, int n_in,
                              void* d_out, int out_size, void* d_ws, size_t ws_size,
                              hipStream_t stream) {
    (void)in_sizes; (void)n_in; (void)out_size; (void)ws_size;
    char* w = (char*)d_ws;
    unsigned short* Wt  = (unsigned short*)w; w += aln((size_t)S1 * 2);
    unsigned short* xb  = (unsigned short*)w; w += aln((size_t)2 * XL * 2);          // 2 layer slots
    unsigned short* msg = (unsigned short*)w; w += aln((size_t)2 * NEP * 32 * 2);    // 12.8 MB
    int* hist = (int*)w; w += aln((size_t)2 * NN * 4);
    int* ptr  = (int*)w; w += aln((size_t)2 * (NN + 1) * 4);
    int* slot = (int*)w; w += aln((size_t)2 * NE * 4);
    float* gbuf = (float*)w; w += aln((size_t)NG * 64 * 4);

    const int* ep = (const int*)d_in[4];
    const int* ed = (const int*)d_in[5];

    PrepArgs pa;
    for (int L4 = 0; L4 < 4; ++L4) {
        int base = 8 + (L4 >> 1) * 12 + (L4 & 1) * 6;
        pa.w2[L4] = (const float*)d_in[base + 2];
        pa.b2[L4] = (const float*)d_in[base + 3];
    }
    pa.x0[0] = (const float*)d_in[0];
    pa.x0[1] = (const float*)d_in[1];
    prep_kernel<<<(S1 + S2V + S3 + S4 + 255) / 256, 256, 0, stream>>>(pa, Wt, xb, hist, gbuf);

    hist_kernel<<<(2 * NE + 255) / 256, 256, 0, stream>>>(ep, ed, hist, slot);
    scan_kernel<<<2, 1024, 0, stream>>>(hist, ptr);

    EdgeArgs ea; GatherArgs ga;
    for (int br = 0; br < 2; ++br) {
        ea.ea[br]    = (const float*)d_in[2 + br];
        ea.eidx[br]  = (const int*)d_in[4 + br];
        ga.batch[br] = (const int*)d_in[6 + br];
    }
    for (int L = 0; L < 2; ++L) {
        for (int br = 0; br < 2; ++br) {
            int base = 8 + br * 12 + L * 6;
            ea.w1[br]   = (const float*)d_in[base + 0];
            ea.b1[br]   = (const float*)d_in[base + 1];
            ga.root[br] = (const float*)d_in[base + 4];
            ga.bias[br] = (const float*)d_in[base + 5];
        }
        edge_kernel<<<512, 256, 0, stream>>>(ea, L, Wt, xb, ptr, slot, msg);
        if (L == 0)
            gather_kernel<0><<<6250, 256, 0, stream>>>(ga, ptr, msg,
                xb, xb + (size_t)XL, gbuf);
        else
            gather_kernel<1><<<6250, 256, 0, stream>>>(ga, ptr, msg,
                xb + (size_t)XL, nullptr, gbuf);
    }

    final_mlp_kernel<<<NG, 64, 0, stream>>>(gbuf,
        (const float*)d_in[32], (const float*)d_in[33],
        (const float*)d_in[34], (const float*)d_in[35],
        (float*)d_out);
}